// Round 14
// baseline (477.581 us; speedup 1.0000x reference)
//
#include <hip/hip_runtime.h>
#include <hip/hip_fp16.h>

// Sizes fixed by the reference.
#define BB 2
#define HH 16
#define SS 2048
#define DD 128
#define CH 64              // keys per staged K chunk (16 KB f16)
#define NCH 32             // SS / CH
#define QBLK 32            // q-rows per block
#define CSHIFT 14.0f       // E' = exp(s-14); s max ~16 -> E' f16-safe; shift cancels in softmax

typedef __attribute__((ext_vector_type(8))) _Float16 f16x8;
typedef __attribute__((ext_vector_type(4))) _Float16 f16x4;
typedef __attribute__((ext_vector_type(4))) float    f32x4;

__device__ __forceinline__ void load_lds16(const void* g, void* l) {
  __builtin_amdgcn_global_load_lds(
      (const __attribute__((address_space(1))) void*)g,
      (__attribute__((address_space(3))) void*)l, 16, 0, 0);
}

__device__ __forceinline__ void block_barrier() {
  asm volatile("" ::: "memory");
  __builtin_amdgcn_s_barrier();
  asm volatile("" ::: "memory");
}

// k_norm = k / max(||k||_2 over HEAD axis, eps), f16, PRE-SWIZZLED row layout:
// (s,d) at s*128 + (((d>>3)^(s&7))<<3) + (d&7). Linear global_load_lds then
// gives conflict-free XOR-swizzled fragment reads in LDS.
__global__ void knorm_f16(const float* __restrict__ k, _Float16* __restrict__ kh) {
  int t = blockIdx.x * 256 + threadIdx.x;      // [0, B*S*D)
  int d = t & (DD - 1);
  int s = (t >> 7) & (SS - 1);
  int b = t >> 18;                              // S*D = 2^18
  const float* kp = k + (size_t)b * HH * SS * DD + (size_t)s * DD + d;
  float vals[HH];
  float ss = 0.f;
  #pragma unroll
  for (int h = 0; h < HH; ++h) { float x = kp[(size_t)h * SS * DD]; vals[h] = x; ss += x * x; }
  float r = 1.0f / fmaxf(sqrtf(ss), 1e-12f);
  const int doff = (((d >> 3) ^ (s & 7)) << 3) + (d & 7);
  _Float16* op = kh + (size_t)b * HH * SS * DD + (size_t)s * DD + doff;
  #pragma unroll
  for (int h = 0; h < HH; ++h) op[(size_t)h * SS * DD] = (_Float16)(vals[h] * r);
}

// q -> f16, 8 elements/thread (plain layout).
__global__ void cvt_f16(const float* __restrict__ x, _Float16* __restrict__ y) {
  size_t i = ((size_t)blockIdx.x * 256 + threadIdx.x) * 8;
  float4 a = *(const float4*)(x + i);
  float4 b = *(const float4*)(x + i + 4);
  f16x8 r = { (_Float16)a.x, (_Float16)a.y, (_Float16)a.z, (_Float16)a.w,
              (_Float16)b.x, (_Float16)b.y, (_Float16)b.z, (_Float16)b.w };
  *(f16x8*)(y + i) = r;
}

// v[b,h,s,d] -> plain V^T [b,h,d,s] f16 (PV B-operand read DIRECT from global:
// 16B/lane contiguous per (d, key-octet); no LDS staging, no swizzle needed).
__global__ void vtrans_f16(const float* __restrict__ v, _Float16* __restrict__ vt) {
  __shared__ float tile[32][33];
  int bh = blockIdx.z;
  int d0 = blockIdx.x * 32, s0 = blockIdx.y * 32;
  const float* vp = v + (size_t)bh * SS * DD;
  _Float16* tp = vt + (size_t)bh * SS * DD;
  int tx = threadIdx.x, ty = threadIdx.y;       // block (32,8)
  #pragma unroll
  for (int i = ty; i < 32; i += 8)
    tile[i][tx] = vp[(size_t)(s0 + i) * DD + d0 + tx];
  __syncthreads();
  #pragma unroll
  for (int i = ty; i < 32; i += 8)
    tp[(size_t)(d0 + i) * SS + s0 + tx] = (_Float16)tile[tx][i];
}

// ---------------- Fused attention (r14): 1 barrier/chunk, V-direct ----------
// 512 thr (8 waves), QBLK=32, CH=64. Wave w = (qhf=w>>2) q-half x (sub=w&3)
// 16-key / 32-dcol subtile. Software-pipelined phases, ONE barrier each:
//   phase c: issue K(c+1) staging; QK^T(c) -> E'=exp(s-14) in regs + pbuf[c&1];
//            PV(c-1) from pbuf[(c-1)&1] + V^T DIRECT from global (L2-hot);
//            lgkmcnt(0); vmcnt(0); barrier.
// Register discipline (the r5/r13 lesson): acc_h 64 + qf 16 + oacc[2] 8 +
// transient vf/pf/addr ~25 -> ~115 < 128 cap, no spill. LDS 41 KB -> 2 blk/CU.
__global__ __launch_bounds__(512, 4) void attn_fused(
    const _Float16* __restrict__ qh, const _Float16* __restrict__ kh,
    const _Float16* __restrict__ vth, const int* __restrict__ mask,
    float* __restrict__ out, float* __restrict__ attn)
{
  __shared__ _Float16 kbuf[2][CH * DD];      // 32 KB
  __shared__ _Float16 pbuf[2][QBLK * CH];    // 8 KB
  __shared__ float redsum[2][16][5];         // [q-half][q][sub], padded

  // XCD swizzle: wgid%8 = XCD; each XCD owns 4 heads, walks their q-tiles.
  const int wgid = blockIdx.x;                  // [0, 2048)
  const int xcd  = wgid & 7;
  const int idx  = wgid >> 3;                   // [0, 256)
  const int bh   = (xcd << 2) | (idx >> 6);     // 4 heads per XCD
  const int q0   = (idx & 63) * QBLK;
  const int b    = bh >> 4;

  const int tid  = threadIdx.x;
  const int lane = tid & 63;
  const int w    = tid >> 6;                    // [0,8)
  const int lo16 = lane & 15;
  const int g    = lane >> 4;
  const int qhf  = w >> 2;                      // q-half
  const int sub  = w & 3;                       // key/d subtile

  const size_t hoff = (size_t)bh * SS * DD;
  const _Float16* Q = qh  + hoff + (size_t)q0 * DD;
  const _Float16* K = kh  + hoff;               // pre-swizzled [2048][128]
  const _Float16* V = vth + hoff;               // plain V^T [128][2048]
  const int* mrow = mask + b * SS;

  const int prow = qhf * 16 + lo16;             // this lane's q row

  f16x8 qf[4];
  #pragma unroll
  for (int c = 0; c < 4; ++c)
    qf[c] = *(const f16x8*)(Q + (size_t)prow * DD + c * 32 + g * 8);

  // ---- Prologue: stage K chunk 0 (512 thr x 2 x 16 B = 16 KB) ----
  #pragma unroll
  for (int j = 0; j < 2; ++j) {
    const int slot = tid + j * 512;
    load_lds16(K + slot * 8, &kbuf[0][slot * 8]);
  }
  __syncthreads();

  f16x4 acc_h[NCH];                             // E' (4 keys/lane/chunk), 64 VGPRs
  f32x4 oacc[2] = { {0,0,0,0}, {0,0,0,0} };
  float ssum = 0.f;

  #pragma unroll
  for (int c = 0; c < NCH; ++c) {
    const _Float16* kb = kbuf[c & 1];

    // ---- issue K staging for chunk c+1 ----
    if (c + 1 < NCH) {
      #pragma unroll
      for (int j = 0; j < 2; ++j) {
        const int slot = tid + j * 512;
        load_lds16(K + (size_t)(c + 1) * (CH * DD) + slot * 8,
                   &kbuf[(c + 1) & 1][slot * 8]);
      }
    }

    // ---- QK^T(c): keys [sub*16,+16) x q-half qhf ----
    {
      const int row = sub * 16 + lo16;          // key row within chunk [0,64)
      f32x4 a = {0.f, 0.f, 0.f, 0.f};
      #pragma unroll
      for (int cc = 0; cc < 4; ++cc) {
        const int p = (cc * 4 + g) ^ (row & 7); // swizzled 16B slot
        f16x8 kf = *(const f16x8*)(kb + row * DD + p * 8);
        a = __builtin_amdgcn_mfma_f32_16x16x32_f16(kf, qf[cc], a, 0, 0, 0);
      }
      // D[key][q]: lane holds q=prow, keys sub*16 + g*4 + i
      const int4 mv = *(const int4*)(mrow + c * CH + sub * 16 + g * 4);
      const float e0 = mv.x ? __expf(a[0] - CSHIFT) : 0.f;
      const float e1 = mv.y ? __expf(a[1] - CSHIFT) : 0.f;
      const float e2 = mv.z ? __expf(a[2] - CSHIFT) : 0.f;
      const float e3 = mv.w ? __expf(a[3] - CSHIFT) : 0.f;
      ssum += e0 + e1 + e2 + e3;
      f16x4 eh = { (_Float16)e0, (_Float16)e1, (_Float16)e2, (_Float16)e3 };
      acc_h[c] = eh;
      const int col = sub * 16 + g * 4;         // key col in pbuf row [0,64)
      *(f16x4*)(&pbuf[c & 1][prow * CH + (((col >> 3) ^ (prow & 7)) << 3) + (col & 7)]) = eh;
    }

    // ---- PV(c-1): d-cols [sub*32,+32) x q-half qhf; V direct from global ----
    if (c > 0) {
      const int kc = (c - 1) * CH;
      #pragma unroll
      for (int t = 0; t < 2; ++t) {
        const int dcol = sub * 32 + t * 16 + lo16;
        #pragma unroll
        for (int ks = 0; ks < 2; ++ks) {
          f16x8 vf = *(const f16x8*)(V + (size_t)dcol * SS + kc + ks * 32 + g * 8);
          f16x8 pf = *(const f16x8*)(&pbuf[(c - 1) & 1]
                       [prow * CH + ((ks * 32 + g * 8) ^ ((prow & 7) << 3))]);
          oacc[t] = __builtin_amdgcn_mfma_f32_16x16x32_f16(pf, vf, oacc[t], 0, 0, 0);
        }
      }
    }

    asm volatile("s_waitcnt lgkmcnt(0)" ::: "memory");  // pbuf(c) visible
    asm volatile("s_waitcnt vmcnt(0)"  ::: "memory");   // K(c+1) resident
    block_barrier();                                    // ONE barrier per chunk
  }

  // ---- Tail: PV(NCH-1) (pbuf written before the last barrier) ----
  {
    const int kc = (NCH - 1) * CH;
    #pragma unroll
    for (int t = 0; t < 2; ++t) {
      const int dcol = sub * 32 + t * 16 + lo16;
      #pragma unroll
      for (int ks = 0; ks < 2; ++ks) {
        f16x8 vf = *(const f16x8*)(V + (size_t)dcol * SS + kc + ks * 32 + g * 8);
        f16x8 pf = *(const f16x8*)(&pbuf[(NCH - 1) & 1]
                     [prow * CH + ((ks * 32 + g * 8) ^ ((prow & 7) << 3))]);
        oacc[t] = __builtin_amdgcn_mfma_f32_16x16x32_f16(pf, vf, oacc[t], 0, 0, 0);
      }
    }
  }

  // ---- Epilogue: denominators, attn from regs, out from oacc ----
  ssum += __shfl_xor(ssum, 16);                 // reduce over g groups
  ssum += __shfl_xor(ssum, 32);
  if (lane < 16) redsum[qhf][lane][sub] = ssum;
  __syncthreads();

  float denom = 0.f;
  #pragma unroll
  for (int j = 0; j < 4; ++j) denom += redsum[qhf][lo16][j];
  const float inv = 1.0f / denom;

  // attn[q0+prow][c*64 + sub*16 + g*4 ..+3] = E' * inv (f32, from registers)
  float* arow = attn + ((size_t)bh * SS + q0 + prow) * SS + sub * 16 + g * 4;
  #pragma unroll
  for (int c = 0; c < NCH; ++c) {
    f32x4 pst = { (float)acc_h[c][0] * inv, (float)acc_h[c][1] * inv,
                  (float)acc_h[c][2] * inv, (float)acc_h[c][3] * inv };
    *(f32x4*)(arow + c * CH) = pst;
  }

  // out: C row = q = qhf*16 + g*4 + i, col = d = sub*32 + t*16 + lo16
  float* O = out + hoff + (size_t)q0 * DD + sub * 32;
  #pragma unroll
  for (int i = 0; i < 4; ++i) {
    const int qr = g * 4 + i;
    float dq = 0.f;
    #pragma unroll
    for (int j = 0; j < 4; ++j) dq += redsum[qhf][qr][j];
    const float rdq = 1.0f / dq;
    #pragma unroll
    for (int t = 0; t < 2; ++t)
      O[(size_t)(qhf * 16 + qr) * DD + t * 16 + lo16] = oacc[t][i] * rdq;
  }
}

extern "C" void kernel_launch(void* const* d_in, const int* in_sizes, int n_in,
                              void* d_out, int out_size, void* d_ws, size_t ws_size,
                              hipStream_t stream) {
  const float* q    = (const float*)d_in[0];
  const float* k    = (const float*)d_in[1];
  const float* v    = (const float*)d_in[2];
  const int*   mask = (const int*)d_in[3];

  const size_t N = (size_t)BB * HH * SS * DD;     // 8388608
  float* out  = (float*)d_out;
  float* attn = out + N;                          // outputs concatenated (out, attn)

  // scratch: 3 f16 tensors = 48 MB
  _Float16* qh  = (_Float16*)d_ws;
  _Float16* kh  = qh + N;
  _Float16* vth = kh + N;

  cvt_f16  <<<N / 8 / 256, 256, 0, stream>>>(q, qh);
  knorm_f16<<<(BB * SS * DD) / 256, 256, 0, stream>>>(k, kh);
  vtrans_f16<<<dim3(DD / 32, SS / 32, BB * HH), dim3(32, 8), 0, stream>>>(v, vth);

  // 64 q-tiles x 32 heads, XCD-swizzled inside the kernel
  attn_fused<<<2048, 512, 0, stream>>>(qh, kh, vth, mask, out, attn);
}

// Round 15
// 313.116 us; speedup vs baseline: 1.5253x; 1.5253x over previous
//
#include <hip/hip_runtime.h>
#include <hip/hip_fp16.h>

// Sizes fixed by the reference.
#define BB 2
#define HH 16
#define SS 2048
#define DD 128
#define CH 64              // keys per staged K/V chunk (16 KB f16 each)
#define NCH 32             // SS / CH
#define QBLK 32            // q-rows per block
#define CSHIFT 14.0f       // E' = exp(s-14); s max ~16 -> E' f16-safe; shift cancels in softmax

typedef __attribute__((ext_vector_type(8))) _Float16 f16x8;
typedef __attribute__((ext_vector_type(4))) _Float16 f16x4;
typedef __attribute__((ext_vector_type(4))) float    f32x4;

__device__ __forceinline__ void load_lds16(const void* g, void* l) {
  __builtin_amdgcn_global_load_lds(
      (const __attribute__((address_space(1))) void*)g,
      (__attribute__((address_space(3))) void*)l, 16, 0, 0);
}

__device__ __forceinline__ void block_barrier() {
  asm volatile("" ::: "memory");
  __builtin_amdgcn_s_barrier();
  asm volatile("" ::: "memory");
}

// k_norm = k / max(||k||_2 over HEAD axis, eps), f16, PRE-SWIZZLED row layout:
// (s,d) at s*128 + (((d>>3)^(s&7))<<3) + (d&7). Linear global_load_lds then
// gives conflict-free XOR-swizzled fragment reads in LDS.
__global__ void knorm_f16(const float* __restrict__ k, _Float16* __restrict__ kh) {
  int t = blockIdx.x * 256 + threadIdx.x;      // [0, B*S*D)
  int d = t & (DD - 1);
  int s = (t >> 7) & (SS - 1);
  int b = t >> 18;                              // S*D = 2^18
  const float* kp = k + (size_t)b * HH * SS * DD + (size_t)s * DD + d;
  float vals[HH];
  float ss = 0.f;
  #pragma unroll
  for (int h = 0; h < HH; ++h) { float x = kp[(size_t)h * SS * DD]; vals[h] = x; ss += x * x; }
  float r = 1.0f / fmaxf(sqrtf(ss), 1e-12f);
  const int doff = (((d >> 3) ^ (s & 7)) << 3) + (d & 7);
  _Float16* op = kh + (size_t)b * HH * SS * DD + (size_t)s * DD + doff;
  #pragma unroll
  for (int h = 0; h < HH; ++h) op[(size_t)h * SS * DD] = (_Float16)(vals[h] * r);
}

// q -> f16, 8 elements/thread (plain layout).
__global__ void cvt_f16(const float* __restrict__ x, _Float16* __restrict__ y) {
  size_t i = ((size_t)blockIdx.x * 256 + threadIdx.x) * 8;
  float4 a = *(const float4*)(x + i);
  float4 b = *(const float4*)(x + i + 4);
  f16x8 r = { (_Float16)a.x, (_Float16)a.y, (_Float16)a.z, (_Float16)a.w,
              (_Float16)b.x, (_Float16)b.y, (_Float16)b.z, (_Float16)b.w };
  *(f16x8*)(y + i) = r;
}

// v[b,h,s,d] -> V^T in 64-key chunk-major swizzled layout: chunk c = key>>6 is
// a 16 KB block [d][64 keys]; element (d,key) at
// c*8192 + d*64 + ((((key&63)>>3) ^ (d&7))<<3) + (key&7).
__global__ void vtrans_f16(const float* __restrict__ v, _Float16* __restrict__ vt) {
  __shared__ float tile[32][33];
  int bh = blockIdx.z;
  int d0 = blockIdx.x * 32, s0 = blockIdx.y * 32;
  const float* vp = v + (size_t)bh * SS * DD;
  _Float16* tp = vt + (size_t)bh * SS * DD;
  int tx = threadIdx.x, ty = threadIdx.y;       // block (32,8)
  #pragma unroll
  for (int i = ty; i < 32; i += 8)
    tile[i][tx] = vp[(size_t)(s0 + i) * DD + d0 + tx];
  __syncthreads();
  #pragma unroll
  for (int i = ty; i < 32; i += 8) {
    const int key = s0 + tx, dd = d0 + i;
    tp[(size_t)(key >> 6) * (DD * CH) + (size_t)dd * CH
       + ((((key & 63) >> 3) ^ (dd & 7)) << 3) + (key & 7)] = (_Float16)tile[tx][i];
  }
}

// ---------------- Fused attention (r15): r11 + 1 barrier/chunk --------------
// 512 thr (8 waves), QBLK=32, CH=64, 2 blocks/CU. Wave w = (qhf=w>>2) q-half
// x (sub=w&3). Software-pipelined, ONE barrier per chunk:
//   phase c: issue K(c+1)->kbuf[(c+1)&1] and V(c)->vbuf[c&1];
//            QK^T(c) -> E'=exp(s-14) regs + pbuf[c&1];
//            PV(c-1) from vbuf[(c-1)&1] + pbuf[(c-1)&1]   (parities disjoint);
//            lgkmcnt(0); vmcnt(0); barrier.
// vs r11: barriers 64 -> 33. vs r14: V staged through LDS again (V-direct's
// 16-line scattered reads were the regression). Regs ~115 < 128: no spill.
__global__ __launch_bounds__(512, 4) void attn_fused(
    const _Float16* __restrict__ qh, const _Float16* __restrict__ kh,
    const _Float16* __restrict__ vth, const int* __restrict__ mask,
    float* __restrict__ out, float* __restrict__ attn)
{
  __shared__ _Float16 kbuf[2][CH * DD];      // 32 KB
  __shared__ _Float16 vbuf[2][DD * CH];      // 32 KB
  __shared__ _Float16 pbuf[2][QBLK * CH];    // 8 KB
  __shared__ float redsum[2][16][5];         // [q-half][q][sub], padded

  // XCD swizzle: wgid%8 = XCD; each XCD owns 4 heads, walks their q-tiles.
  const int wgid = blockIdx.x;                  // [0, 2048)
  const int xcd  = wgid & 7;
  const int idx  = wgid >> 3;                   // [0, 256)
  const int bh   = (xcd << 2) | (idx >> 6);     // 4 heads per XCD
  const int q0   = (idx & 63) * QBLK;
  const int b    = bh >> 4;

  const int tid  = threadIdx.x;
  const int lane = tid & 63;
  const int w    = tid >> 6;                    // [0,8)
  const int lo16 = lane & 15;
  const int g    = lane >> 4;
  const int qhf  = w >> 2;                      // q-half
  const int sub  = w & 3;                       // key/d subtile

  const size_t hoff = (size_t)bh * SS * DD;
  const _Float16* Q = qh  + hoff + (size_t)q0 * DD;
  const _Float16* K = kh  + hoff;               // pre-swizzled [2048][128]
  const _Float16* V = vth + hoff;               // 64-key chunk-major swizzled
  const int* mrow = mask + b * SS;

  const int prow = qhf * 16 + lo16;             // this lane's q row

  f16x8 qf[4];
  #pragma unroll
  for (int c = 0; c < 4; ++c)
    qf[c] = *(const f16x8*)(Q + (size_t)prow * DD + c * 32 + g * 8);

  // ---- Prologue: stage K chunk 0 (512 thr x 2 x 16 B = 16 KB) ----
  #pragma unroll
  for (int j = 0; j < 2; ++j) {
    const int slot = tid + j * 512;
    load_lds16(K + slot * 8, &kbuf[0][slot * 8]);
  }
  __syncthreads();

  f16x4 acc_h[NCH];                             // E' (4 keys/lane/chunk), 64 VGPRs
  f32x4 oacc[2] = { {0,0,0,0}, {0,0,0,0} };
  float ssum = 0.f;

  #pragma unroll
  for (int c = 0; c < NCH; ++c) {
    const _Float16* kb = kbuf[c & 1];

    // ---- issue staging: K(c+1) and V(c) ----
    if (c + 1 < NCH) {
      #pragma unroll
      for (int j = 0; j < 2; ++j) {
        const int slot = tid + j * 512;
        load_lds16(K + (size_t)(c + 1) * (CH * DD) + slot * 8,
                   &kbuf[(c + 1) & 1][slot * 8]);
      }
    }
    #pragma unroll
    for (int j = 0; j < 2; ++j) {
      const int slot = tid + j * 512;
      load_lds16(V + (size_t)c * (CH * DD) + slot * 8,
                 &vbuf[c & 1][slot * 8]);
    }

    // ---- QK^T(c): keys [sub*16,+16) x q-half qhf ----
    {
      const int row = sub * 16 + lo16;          // key row within chunk [0,64)
      f32x4 a = {0.f, 0.f, 0.f, 0.f};
      #pragma unroll
      for (int cc = 0; cc < 4; ++cc) {
        const int p = (cc * 4 + g) ^ (row & 7); // swizzled 16B slot
        f16x8 kf = *(const f16x8*)(kb + row * DD + p * 8);
        a = __builtin_amdgcn_mfma_f32_16x16x32_f16(kf, qf[cc], a, 0, 0, 0);
      }
      // D[key][q]: lane holds q=prow, keys sub*16 + g*4 + i
      const int4 mv = *(const int4*)(mrow + c * CH + sub * 16 + g * 4);
      const float e0 = mv.x ? __expf(a[0] - CSHIFT) : 0.f;
      const float e1 = mv.y ? __expf(a[1] - CSHIFT) : 0.f;
      const float e2 = mv.z ? __expf(a[2] - CSHIFT) : 0.f;
      const float e3 = mv.w ? __expf(a[3] - CSHIFT) : 0.f;
      ssum += e0 + e1 + e2 + e3;
      f16x4 eh = { (_Float16)e0, (_Float16)e1, (_Float16)e2, (_Float16)e3 };
      acc_h[c] = eh;
      const int col = sub * 16 + g * 4;         // key col in pbuf row [0,64)
      *(f16x4*)(&pbuf[c & 1][prow * CH + (((col >> 3) ^ (prow & 7)) << 3) + (col & 7)]) = eh;
    }

    // ---- PV(c-1): d-cols [sub*32,+32) x q-half qhf, from vbuf[(c-1)&1] ----
    if (c > 0) {
      const _Float16* vb = vbuf[(c - 1) & 1];
      const _Float16* pb = pbuf[(c - 1) & 1];
      #pragma unroll
      for (int t = 0; t < 2; ++t) {
        const int dcol = sub * 32 + t * 16 + lo16;
        #pragma unroll
        for (int ks = 0; ks < 2; ++ks) {
          const int pv_ = (ks * 4 + g) ^ (dcol & 7);
          f16x8 vf = *(const f16x8*)(vb + dcol * CH + pv_ * 8);
          f16x8 pf = *(const f16x8*)(pb + prow * CH + ((ks * 32 + g * 8) ^ ((prow & 7) << 3)));
          oacc[t] = __builtin_amdgcn_mfma_f32_16x16x32_f16(pf, vf, oacc[t], 0, 0, 0);
        }
      }
    }

    asm volatile("s_waitcnt lgkmcnt(0)" ::: "memory");  // pbuf(c) visible
    asm volatile("s_waitcnt vmcnt(0)"  ::: "memory");   // K(c+1), V(c) resident
    block_barrier();                                    // ONE barrier per chunk
  }

  // ---- Tail: PV(NCH-1) (vbuf/pbuf written before the last barrier) ----
  {
    const _Float16* vb = vbuf[(NCH - 1) & 1];
    const _Float16* pb = pbuf[(NCH - 1) & 1];
    #pragma unroll
    for (int t = 0; t < 2; ++t) {
      const int dcol = sub * 32 + t * 16 + lo16;
      #pragma unroll
      for (int ks = 0; ks < 2; ++ks) {
        const int pv_ = (ks * 4 + g) ^ (dcol & 7);
        f16x8 vf = *(const f16x8*)(vb + dcol * CH + pv_ * 8);
        f16x8 pf = *(const f16x8*)(pb + prow * CH + ((ks * 32 + g * 8) ^ ((prow & 7) << 3)));
        oacc[t] = __builtin_amdgcn_mfma_f32_16x16x32_f16(pf, vf, oacc[t], 0, 0, 0);
      }
    }
  }

  // ---- Epilogue: denominators, attn from regs, out from oacc ----
  ssum += __shfl_xor(ssum, 16);                 // reduce over g groups
  ssum += __shfl_xor(ssum, 32);
  if (lane < 16) redsum[qhf][lane][sub] = ssum;
  __syncthreads();

  float denom = 0.f;
  #pragma unroll
  for (int j = 0; j < 4; ++j) denom += redsum[qhf][lo16][j];
  const float inv = 1.0f / denom;

  // attn[q0+prow][c*64 + sub*16 + g*4 ..+3] = E' * inv (f32, from registers)
  float* arow = attn + ((size_t)bh * SS + q0 + prow) * SS + sub * 16 + g * 4;
  #pragma unroll
  for (int c = 0; c < NCH; ++c) {
    f32x4 pst = { (float)acc_h[c][0] * inv, (float)acc_h[c][1] * inv,
                  (float)acc_h[c][2] * inv, (float)acc_h[c][3] * inv };
    *(f32x4*)(arow + c * CH) = pst;
  }

  // out: C row = q = qhf*16 + g*4 + i, col = d = sub*32 + t*16 + lo16
  float* O = out + hoff + (size_t)q0 * DD + sub * 32;
  #pragma unroll
  for (int i = 0; i < 4; ++i) {
    const int qr = g * 4 + i;
    float dq = 0.f;
    #pragma unroll
    for (int j = 0; j < 4; ++j) dq += redsum[qhf][qr][j];
    const float rdq = 1.0f / dq;
    #pragma unroll
    for (int t = 0; t < 2; ++t)
      O[(size_t)(qhf * 16 + qr) * DD + t * 16 + lo16] = oacc[t][i] * rdq;
  }
}

extern "C" void kernel_launch(void* const* d_in, const int* in_sizes, int n_in,
                              void* d_out, int out_size, void* d_ws, size_t ws_size,
                              hipStream_t stream) {
  const float* q    = (const float*)d_in[0];
  const float* k    = (const float*)d_in[1];
  const float* v    = (const float*)d_in[2];
  const int*   mask = (const int*)d_in[3];

  const size_t N = (size_t)BB * HH * SS * DD;     // 8388608
  float* out  = (float*)d_out;
  float* attn = out + N;                          // outputs concatenated (out, attn)

  // scratch: 3 f16 tensors = 48 MB
  _Float16* qh  = (_Float16*)d_ws;
  _Float16* kh  = qh + N;
  _Float16* vth = kh + N;

  cvt_f16  <<<N / 8 / 256, 256, 0, stream>>>(q, qh);
  knorm_f16<<<(BB * SS * DD) / 256, 256, 0, stream>>>(k, kh);
  vtrans_f16<<<dim3(DD / 32, SS / 32, BB * HH), dim3(32, 8), 0, stream>>>(v, vth);

  // 64 q-tiles x 32 heads, XCD-swizzled inside the kernel
  attn_fused<<<2048, 512, 0, stream>>>(qh, kh, vth, mask, out, attn);
}